// Round 2
// baseline (534.285 us; speedup 1.0000x reference)
//
#include <hip/hip_runtime.h>
#include <hip/hip_cooperative_groups.h>
#include <math.h>

namespace cg = cooperative_groups;

#define IMSZ 28
#define PSZ 8
#define LAMF 0.001f

// Fused 5-step cyclic net. One thread per sample, state+positions in
// registers across steps. Grid = 256 blocks (== CU count, co-resident via
// cooperative launch). Per-step cross-batch coact reduction: block-level LDS
// reduction -> 64B-padded global atomicAdd -> grid.sync -> agent-scope load.
__global__ __launch_bounds__(256) void cyclic_fused(
    const float* __restrict__ x,
    const float* __restrict__ Wi, const float* __restrict__ bi,
    const float* __restrict__ gamma, const float* __restrict__ beta,
    const float* __restrict__ R, const float* __restrict__ rb,
    const float* __restrict__ mask,
    const float* __restrict__ Wc, const float* __restrict__ bc,
    const float* __restrict__ Wo, const float* __restrict__ bo,
    float* __restrict__ coact,     // 4 steps * 225 entries * 16 floats (64B pad), pre-zeroed
    float* __restrict__ out, int B, float invB)
{
    cg::grid_group grid = cg::this_grid();

    __shared__ float sWi[15 * 72];     // padded rows
    __shared__ float sBi[16], sGa[16], sBe[16], sRb[16];
    __shared__ float sWc[32], sBc[2], sWo[160], sBo[16];
    __shared__ float sR[240], sM[240], sReff[240];
    __shared__ float sS[256 * 16];

    const int tid = threadIdx.x;

    // ---- stage all constants once ----
    for (int idx = tid; idx < 990; idx += 256) {
        int u = idx / 66, k = idx - u * 66;
        sWi[u * 72 + k] = Wi[idx];
    }
    if (tid < 225) { sR[tid] = R[tid]; sM[tid] = mask[tid]; }
    if (tid < 15) {
        sBi[tid] = bi[tid]; sGa[tid] = gamma[tid];
        sBe[tid] = beta[tid]; sRb[tid] = rb[tid];
    }
    if (tid < 30)  sWc[tid] = Wc[tid];
    if (tid < 2)   sBc[tid] = bc[tid];
    if (tid < 150) sWo[tid] = Wo[tid];
    if (tid < 10)  sBo[tid] = bo[tid];
    __syncthreads();

    const int b = blockIdx.x * 256 + tid;
    const float* img = x + (size_t)b * (IMSZ * IMSZ);

    int pr = 10, pc = 10;          // (IM-PS)/2
    float st[15];

    for (int s = 0; s < 5; ++s) {
        // ---- patch gather: all 64 loads issued before use ----
        float patch[64];
#pragma unroll
        for (int r = 0; r < 8; ++r) {
            const float* rowp = img + (pr + r) * IMSZ + pc;
#pragma unroll
            for (int c = 0; c < 8; ++c) patch[r * 8 + c] = rowp[c];
        }
        const float posr = ((float)pr / 20.0f) * 2.0f - 1.0f;
        const float posc = ((float)pc / 20.0f) * 2.0f - 1.0f;

        // ---- input + recurrent matvec, relu ----
        float h[15];
#pragma unroll
        for (int u = 0; u < 15; ++u) {
            const float* w = sWi + u * 72;
            float a = 0.0f;
#pragma unroll
            for (int k = 0; k < 64; ++k) a = fmaf(patch[k], w[k], a);
            a = fmaf(posr, w[64], a);
            a = fmaf(posc, w[65], a);
            a += sBi[u];
            if (s > 0) {
                float r2 = 0.0f;
#pragma unroll
                for (int j = 0; j < 15; ++j) r2 = fmaf(st[j], sReff[u * 15 + j], r2);
                a += r2 + sRb[u];
            }
            h[u] = fmaxf(a, 0.0f);
        }

        // ---- LayerNorm over 15 units ----
        float mu = 0.0f;
#pragma unroll
        for (int u = 0; u < 15; ++u) mu += h[u];
        mu *= (1.0f / 15.0f);
        float var = 0.0f;
#pragma unroll
        for (int u = 0; u < 15; ++u) { float d = h[u] - mu; var = fmaf(d, d, var); }
        var *= (1.0f / 15.0f);
        const float rs = 1.0f / sqrtf(var + 1e-5f);
#pragma unroll
        for (int u = 0; u < 15; ++u) st[u] = (h[u] - mu) * rs * sGa[u] + sBe[u];

        if (s == 4) {
            // ---- final logits ----
#pragma unroll
            for (int o = 0; o < 10; ++o) {
                float a = 0.0f;
#pragma unroll
                for (int j = 0; j < 15; ++j) a = fmaf(st[j], sWo[o * 15 + j], a);
                out[(size_t)b * 10 + o] = a + sBo[o];
            }
        } else {
            // ---- stash state for block coact reduction ----
#pragma unroll
            for (int j = 0; j < 15; ++j) sS[tid * 16 + j] = st[j];

            // ---- control head / position update (registers only) ----
            float c0 = 0.0f, c1 = 0.0f;
#pragma unroll
            for (int j = 0; j < 15; ++j) {
                c0 = fmaf(st[j], sWc[j], c0);
                c1 = fmaf(st[j], sWc[15 + j], c1);
            }
            c0 = tanhf(c0 + sBc[0]);
            c1 = tanhf(c1 + sBc[1]);
            const float m0 = fabsf(c0), m1 = fabsf(c1);
            int rm, cm;
            if (m0 >= m1) { rm = (c0 > 0.0f) - (c0 < 0.0f); cm = 0; }
            else          { rm = 0; cm = (c1 > 0.0f) - (c1 < 0.0f); }
            pr = min(max(pr + rm, 0), IMSZ - PSZ);
            pc = min(max(pc + cm, 0), IMSZ - PSZ);

            __syncthreads();
            // ---- block-level outer-product reduction, 64B-padded atomics ----
            if (tid < 225) {
                int i = tid / 15, j = tid - i * 15;
                float acc = 0.0f;
#pragma unroll 8
                for (int bb = 0; bb < 256; ++bb)
                    acc = fmaf(sS[bb * 16 + i], sS[bb * 16 + j], acc);
                atomicAdd(&coact[(size_t)(s * 225 + tid) * 16], acc);
            }

            grid.sync();

            // ---- build effective recurrent matrix for next step ----
            if (tid < 225) {
                float cv = __hip_atomic_load(&coact[(size_t)(s * 225 + tid) * 16],
                                             __ATOMIC_ACQUIRE, __HIP_MEMORY_SCOPE_AGENT);
                sReff[tid] = (sR[tid] - LAMF * (cv * invB)) * sM[tid];
            }
            __syncthreads();
        }
    }
}

extern "C" void kernel_launch(void* const* d_in, const int* in_sizes, int n_in,
                              void* d_out, int out_size, void* d_ws, size_t ws_size,
                              hipStream_t stream) {
    const float* x     = (const float*)d_in[0];
    const float* Wi    = (const float*)d_in[1];
    const float* bi    = (const float*)d_in[2];
    const float* gamma = (const float*)d_in[3];
    const float* beta  = (const float*)d_in[4];
    const float* R     = (const float*)d_in[5];
    const float* rb    = (const float*)d_in[6];
    const float* mask  = (const float*)d_in[7];
    const float* Wc    = (const float*)d_in[8];
    const float* bc    = (const float*)d_in[9];
    const float* Wo    = (const float*)d_in[10];
    const float* bo    = (const float*)d_in[11];
    float* out = (float*)d_out;

    int B = in_sizes[0] / (IMSZ * IMSZ);
    float invB = 1.0f / (float)B;
    float* coact = (float*)d_ws;           // 4*225*16 floats used

    hipMemsetAsync(coact, 0, (size_t)4 * 240 * 16 * sizeof(float), stream);

    void* args[] = { (void*)&x, (void*)&Wi, (void*)&bi, (void*)&gamma, (void*)&beta,
                     (void*)&R, (void*)&rb, (void*)&mask, (void*)&Wc, (void*)&bc,
                     (void*)&Wo, (void*)&bo, (void*)&coact, (void*)&out,
                     (void*)&B, (void*)&invB };

    hipLaunchCooperativeKernel((void*)cyclic_fused, dim3(B / 256), dim3(256),
                               args, 0, stream);
}

// Round 3
// 353.277 us; speedup vs baseline: 1.5124x; 1.5124x over previous
//
#include <hip/hip_runtime.h>
#include <math.h>

#define IMSZ 28
#define PSZ  8
#define LAMF 0.001f
#define NREP 8          // coact atomic replica buffers (separate cache lines)
#define CSTRIDE 240     // floats per replica (225 used, padded)

// 8 lanes per sample (lane = patch row). Lane computes k-partials of the
// 15-unit input matvec over its 8 patch floats + its 2 recurrent columns;
// 3-stage __shfl_xor butterfly broadcasts full sums to all 8 lanes; LN /
// control head redundant per lane. 5 sequential launches; coact crosses
// kernels via 8-replica atomicAdd buffers; state AoS [b][16] in workspace.
template<bool FIRST, bool LAST>
__global__ __launch_bounds__(256, 8) void step8(
    const float* __restrict__ x,
    const float* __restrict__ Wi, const float* __restrict__ bi,
    const float* __restrict__ gamma, const float* __restrict__ beta,
    const float* __restrict__ R, const float* __restrict__ rb,
    const float* __restrict__ mask,
    const float* __restrict__ Wc, const float* __restrict__ bc,
    const float* __restrict__ Wo, const float* __restrict__ bo,
    float* __restrict__ state, int* __restrict__ pos,
    const float* __restrict__ coact_in, float* __restrict__ coact_out,
    float* __restrict__ out, int B, float invB)
{
    __shared__ float sWi[15 * 72];          // row stride 72 -> 2-way banks (free)
    __shared__ float sBi[16], sGa[16], sBe[16], sRb[16];
    __shared__ float sWc[32], sBc[2], sWo[160], sBo[16];
    __shared__ float sReff[240];
    __shared__ float sS[32 * 16];

    const int tid = threadIdx.x;

    // ---- stage constants ----
    for (int idx = tid; idx < 990; idx += 256) {
        int u = idx / 66, k = idx - u * 66;
        sWi[u * 72 + k] = Wi[idx];
    }
    if (tid < 15) {
        sBi[tid] = bi[tid]; sGa[tid] = gamma[tid];
        sBe[tid] = beta[tid]; sRb[tid] = rb[tid];
    }
    if (tid >= 32 && tid < 62) sWc[tid - 32] = Wc[tid - 32];
    if (tid >= 64 && tid < 66) sBc[tid - 64] = bc[tid - 64];
    if (LAST) {
        if (tid >= 96 && tid < 246) sWo[tid - 96] = Wo[tid - 96];
        if (tid >= 246) sBo[tid - 246] = bo[tid - 246];
    }
    if (!FIRST) {
        if (tid < 225) {
            float cv = 0.0f;
#pragma unroll
            for (int r = 0; r < NREP; ++r) cv += coact_in[r * CSTRIDE + tid];
            sReff[tid] = (R[tid] - LAMF * (cv * invB)) * mask[tid];
        } else if (tid < 240) {
            sReff[tid] = 0.0f;              // safe pad for row==7 dummy column
        }
    }
    __syncthreads();

    const int sib = tid >> 3;               // sample in block (0..31)
    const int row = tid & 7;                // patch row handled by this lane
    const int b = blockIdx.x * 32 + sib;

    int pr, pc;
    if (FIRST) { pr = 10; pc = 10; }
    else { int p = pos[b]; pr = p >> 8; pc = p & 255; }

    // ---- patch row gather (8 floats) ----
    const float* rowp = x + (size_t)b * (IMSZ * IMSZ) + (pr + row) * IMSZ + pc;
    float patch[8];
#pragma unroll
    for (int c = 0; c < 8; ++c) patch[c] = rowp[c];

    const float posr = ((float)pr / 20.0f) * 2.0f - 1.0f;
    const float posc = ((float)pc / 20.0f) * 2.0f - 1.0f;

    // previous state: this lane's two recurrent columns
    float sj0 = 0.0f, sj1 = 0.0f;
    if (!FIRST) {
        sj0 = state[b * 16 + row];
        sj1 = (row < 7) ? state[b * 16 + 8 + row] : 0.0f;
    }

    // ---- k-partial matvec ----
    float h[15];
#pragma unroll
    for (int u = 0; u < 15; ++u) {
        const float* w = sWi + u * 72 + row * 8;
        float a = 0.0f;
#pragma unroll
        for (int c = 0; c < 8; ++c) a = fmaf(patch[c], w[c], a);
        if (!FIRST) {
            a = fmaf(sj0, sReff[u * 15 + row], a);
            a = fmaf(sj1, sReff[u * 15 + 8 + row], a);
        }
        if (row == 0) {
            a = fmaf(posr, sWi[u * 72 + 64], a);
            a = fmaf(posc, sWi[u * 72 + 65], a);
            a += sBi[u];
            if (!FIRST) a += sRb[u];
        }
        h[u] = a;
    }

    // ---- butterfly reduce within 8-lane group, relu ----
#pragma unroll
    for (int u = 0; u < 15; ++u) {
        float v = h[u];
        v += __shfl_xor(v, 1);
        v += __shfl_xor(v, 2);
        v += __shfl_xor(v, 4);
        h[u] = fmaxf(v, 0.0f);
    }

    // ---- LayerNorm (redundant per lane) ----
    float mu = 0.0f;
#pragma unroll
    for (int u = 0; u < 15; ++u) mu += h[u];
    mu *= (1.0f / 15.0f);
    float var = 0.0f;
#pragma unroll
    for (int u = 0; u < 15; ++u) { float d = h[u] - mu; var = fmaf(d, d, var); }
    var *= (1.0f / 15.0f);
    const float rs = 1.0f / sqrtf(var + 1e-5f);
    float st[15];
#pragma unroll
    for (int u = 0; u < 15; ++u) st[u] = (h[u] - mu) * rs * sGa[u] + sBe[u];

    if (LAST) {
        // ---- logits: rows 0..7 -> o=row, rows 0..1 also o=8+row ----
#pragma unroll
        for (int rep = 0; rep < 2; ++rep) {
            int o = rep * 8 + row;
            if (o < 10) {
                float a = 0.0f;
#pragma unroll
                for (int j = 0; j < 15; ++j) a = fmaf(st[j], sWo[o * 15 + j], a);
                out[(size_t)b * 10 + o] = a + sBo[o];
            }
        }
    } else {
        // ---- persist state AoS [b][16] ----
        state[b * 16 + row] = st[row];
        if (row < 7) state[b * 16 + 8 + row] = st[8 + row];

        // ---- control head / position update (redundant per lane) ----
        float c0 = 0.0f, c1 = 0.0f;
#pragma unroll
        for (int j = 0; j < 15; ++j) {
            c0 = fmaf(st[j], sWc[j], c0);
            c1 = fmaf(st[j], sWc[15 + j], c1);
        }
        c0 = tanhf(c0 + sBc[0]);
        c1 = tanhf(c1 + sBc[1]);
        const float m0 = fabsf(c0), m1 = fabsf(c1);
        int rm, cm;
        if (m0 >= m1) { rm = (c0 > 0.0f) - (c0 < 0.0f); cm = 0; }
        else          { rm = 0; cm = (c1 > 0.0f) - (c1 < 0.0f); }
        pr = min(max(pr + rm, 0), IMSZ - PSZ);
        pc = min(max(pc + cm, 0), IMSZ - PSZ);
        if (row == 0) pos[b] = (pr << 8) | pc;

        // ---- coact block reduction -> replica atomics ----
        sS[sib * 16 + row] = st[row];
        if (row < 7) sS[sib * 16 + 8 + row] = st[8 + row];
        __syncthreads();
        if (tid < 225) {
            int i = tid / 15, j = tid - i * 15;
            float acc = 0.0f;
#pragma unroll
            for (int bb = 0; bb < 32; ++bb)
                acc = fmaf(sS[bb * 16 + i], sS[bb * 16 + j], acc);
            atomicAdd(&coact_out[(blockIdx.x & (NREP - 1)) * CSTRIDE + tid], acc);
        }
    }
}

extern "C" void kernel_launch(void* const* d_in, const int* in_sizes, int n_in,
                              void* d_out, int out_size, void* d_ws, size_t ws_size,
                              hipStream_t stream) {
    const float* x     = (const float*)d_in[0];
    const float* Wi    = (const float*)d_in[1];
    const float* bi    = (const float*)d_in[2];
    const float* gamma = (const float*)d_in[3];
    const float* beta  = (const float*)d_in[4];
    const float* R     = (const float*)d_in[5];
    const float* rb    = (const float*)d_in[6];
    const float* mask  = (const float*)d_in[7];
    const float* Wc    = (const float*)d_in[8];
    const float* bc    = (const float*)d_in[9];
    const float* Wo    = (const float*)d_in[10];
    const float* bo    = (const float*)d_in[11];
    float* out = (float*)d_out;

    const int B = in_sizes[0] / (IMSZ * IMSZ);
    const float invB = 1.0f / (float)B;
    const int grid = B / 32;                // 8 threads per sample, 256/block

    // workspace: state B*16 f32 | pos B i32 | coact 4 steps * NREP * CSTRIDE f32
    float* wsf = (float*)d_ws;
    float* state = wsf;
    int* pos = (int*)(wsf + (size_t)B * 16);
    float* coact = wsf + (size_t)B * 16 + (size_t)B;

    hipMemsetAsync(coact, 0, (size_t)4 * NREP * CSTRIDE * sizeof(float), stream);

    step8<true, false><<<grid, 256, 0, stream>>>(
        x, Wi, bi, gamma, beta, R, rb, mask, Wc, bc, Wo, bo,
        state, pos, nullptr, coact + 0 * NREP * CSTRIDE, nullptr, B, invB);
    step8<false, false><<<grid, 256, 0, stream>>>(
        x, Wi, bi, gamma, beta, R, rb, mask, Wc, bc, Wo, bo,
        state, pos, coact + 0 * NREP * CSTRIDE, coact + 1 * NREP * CSTRIDE, nullptr, B, invB);
    step8<false, false><<<grid, 256, 0, stream>>>(
        x, Wi, bi, gamma, beta, R, rb, mask, Wc, bc, Wo, bo,
        state, pos, coact + 1 * NREP * CSTRIDE, coact + 2 * NREP * CSTRIDE, nullptr, B, invB);
    step8<false, false><<<grid, 256, 0, stream>>>(
        x, Wi, bi, gamma, beta, R, rb, mask, Wc, bc, Wo, bo,
        state, pos, coact + 2 * NREP * CSTRIDE, coact + 3 * NREP * CSTRIDE, nullptr, B, invB);
    step8<false, true><<<grid, 256, 0, stream>>>(
        x, Wi, bi, gamma, beta, R, rb, mask, Wc, bc, Wo, bo,
        state, pos, coact + 3 * NREP * CSTRIDE, nullptr, out, B, invB);
}